// Round 9
// baseline (235.712 us; speedup 1.0000x reference)
//
#include <hip/hip_runtime.h>
#include <math.h>

#define S_LEN  4096
#define DMODEL 1024
#define NH     16
#define HD     64

typedef __bf16 bf16;
typedef __attribute__((ext_vector_type(8))) __bf16 bf16x8;
typedef __attribute__((ext_vector_type(4))) __bf16 bf16x4;
typedef __attribute__((ext_vector_type(4))) float  f32x4;

// direct global->LDS, 16B per lane. dest = wave-uniform base + lane*16.
__device__ inline void gl_lds16(const void* g, void* l) {
    __builtin_amdgcn_global_load_lds(
        (const __attribute__((address_space(1))) void*)g,
        (__attribute__((address_space(3))) void*)l, 16, 0, 0);
}

// ---------------------------------------------------------------------------
// fp32 -> bf16 conversion for x, Wq, Wk, Wv, Wo in one launch.
// ---------------------------------------------------------------------------
__global__ __launch_bounds__(256)
void f32_to_bf16_all(const float* __restrict__ x,  const float* __restrict__ wq,
                     const float* __restrict__ wk, const float* __restrict__ wv,
                     const float* __restrict__ wo,
                     bf16* __restrict__ xb,  bf16* __restrict__ wqb,
                     bf16* __restrict__ wkb, bf16* __restrict__ wvb,
                     bf16* __restrict__ wob)
{
    int b = blockIdx.x;
    const float* s; bf16* d; int idx;
    if      (b < 2048) { s = x;  d = xb;  idx = b; }
    else if (b < 2560) { s = wq; d = wqb; idx = b - 2048; }
    else if (b < 3072) { s = wk; d = wkb; idx = b - 2560; }
    else if (b < 3584) { s = wv; d = wvb; idx = b - 3072; }
    else               { s = wo; d = wob; idx = b - 3584; }
    size_t e0 = ((size_t)idx * 256 + threadIdx.x) * 8;
    float4 a = *(const float4*)(s + e0);
    float4 c = *(const float4*)(s + e0 + 4);
    bf16x8 r;
    r[0] = (bf16)a.x; r[1] = (bf16)a.y; r[2] = (bf16)a.z; r[3] = (bf16)a.w;
    r[4] = (bf16)c.x; r[5] = (bf16)c.y; r[6] = (bf16)c.z; r[7] = (bf16)c.w;
    *(bf16x8*)(d + e0) = r;
}

// ---------------------------------------------------------------------------
// bf16 MFMA GEMM, NT: C[m,n] = sum_k A[m,k]*B[n,k].  128x64 tile, BK=32,
// 4 waves (2x2 grid, 64x32 wave-tile, acc[4][2]), 2-phase LDS double-buffer
// with global_load_lds(16B). Smaller BN doubles grid size -> more blocks/CU
// (gemm_out was 1 block/CU at BN=128). NOTE: no LDS swizzle — an XOR of the
// already-lane-varying slot index is a no-op for conflicts (R8 lesson);
// the [row][32] layout's b128 row-read conflict is inherent (m97 had it too).
// ---------------------------------------------------------------------------
template <typename OutT>
__device__ inline void gemm_body(const bf16* __restrict__ A, const bf16* __restrict__ B,
                                 OutT* __restrict__ C, bool trans, int M, int N, int K)
{
    __shared__ __align__(16) bf16 As[2][128 * 32];
    __shared__ __align__(16) bf16 Bs[2][64 * 32];

    const int t = threadIdx.x, lane = t & 63, w = t >> 6;
    const int m0 = blockIdx.x * 128, n0 = blockIdx.y * 64;
    const int wr = (w >> 1) * 64, wc = (w & 1) * 32;
    const int fr = lane & 15, fc = lane >> 4;

    // staging: A-tile 128x32 (2 gl_lds/wave), B-tile 64x32 (1 gl_lds/wave)
    const int  srowA = w * 32 + (lane >> 2);
    const int  srowB = w * 16 + (lane >> 2);
    const int  schk  = (lane & 3) * 8;
    const bf16* Ag = A + (size_t)(m0 + srowA) * K + schk;
    const bf16* Bg = B + (size_t)(n0 + srowB) * K + schk;
    const int  sbaseA = (w * 32) * 32;
    const int  sbaseB = (w * 16) * 32;

    f32x4 acc[4][2] = {};

    auto stage = [&](int buf, int k0) {
        gl_lds16(Ag + k0,                  &As[buf][sbaseA]);
        gl_lds16(Ag + k0 + (size_t)16 * K, &As[buf][sbaseA + 16 * 32]);
        gl_lds16(Bg + k0,                  &Bs[buf][sbaseB]);
    };

    stage(0, 0);
    __syncthreads();
    int cur = 0;
    for (int k0 = 0; k0 < K; k0 += 32) {
        if (k0 + 32 < K) stage(cur ^ 1, k0 + 32);
        bf16x8 af[4], bv[2];
        #pragma unroll
        for (int fm = 0; fm < 4; ++fm)
            af[fm] = *(const bf16x8*)&As[cur][(wr + fm * 16 + fr) * 32 + fc * 8];
        #pragma unroll
        for (int fn = 0; fn < 2; ++fn)
            bv[fn] = *(const bf16x8*)&Bs[cur][(wc + fn * 16 + fr) * 32 + fc * 8];
        #pragma unroll
        for (int fm = 0; fm < 4; ++fm)
            #pragma unroll
            for (int fn = 0; fn < 2; ++fn)
                acc[fm][fn] = __builtin_amdgcn_mfma_f32_16x16x32_bf16(
                                  af[fm], bv[fn], acc[fm][fn], 0, 0, 0);
        __syncthreads();
        cur ^= 1;
    }

    // epilogue: D layout col=lane&15, row=(lane>>4)*4+reg
    #pragma unroll
    for (int fm = 0; fm < 4; ++fm)
        #pragma unroll
        for (int fn = 0; fn < 2; ++fn)
            #pragma unroll
            for (int r = 0; r < 4; ++r) {
                int row = m0 + wr + fm * 16 + fc * 4 + r;
                int col = n0 + wc + fn * 16 + fr;
                float v = acc[fm][fn][r];
                if (trans) C[(size_t)col * M + row] = (OutT)v;
                else       C[(size_t)row * N + col] = (OutT)v;
            }
}

__global__ __launch_bounds__(256)
void gemm_qkv(const bf16* __restrict__ A,
              const bf16* __restrict__ Wq, const bf16* __restrict__ Wk,
              const bf16* __restrict__ Wv,
              bf16* __restrict__ Qo, bf16* __restrict__ Ko, bf16* __restrict__ Vo)
{
    const int z = blockIdx.z;
    const bf16* B = (z == 0) ? Wq : (z == 1) ? Wk : Wv;
    bf16*       C = (z == 0) ? Qo : (z == 1) ? Ko : Vo;
    gemm_body<bf16>(A, B, C, z == 2, S_LEN, DMODEL, DMODEL);
}

__global__ __launch_bounds__(256)
void gemm_out(const bf16* __restrict__ A, const bf16* __restrict__ B,
              float* __restrict__ C)
{
    gemm_body<float>(A, B, C, false, S_LEN, DMODEL, DMODEL);
}

// ---------------------------------------------------------------------------
// MFMA flash attention, causal, NO-MAX softmax, swapped-operand form,
// SEQUENTIAL PAIR-BLOCK: block (h, p) processes q-tile p fully, THEN q-tile
// 63-p, in one flattened 65-step kv loop (uniform duration for every block —
// no causal tail; R7's concurrent pairing doubled VGPR, this keeps one live
// accumulator set). Grid 512 = 2 blocks/CU constant. Double-buffer prefetch
// runs across the pair boundary.
//   S^T = mfma(K,Q): lane holds 16 P values for one q-row -> in-lane softmax,
//   scalar lsum; PV with permuted k-map (k = 8*fc + 4*(fn&1) + r) -> pa built
//   by in-lane cvt (no LDS); V read as 2x ds_read_b64 from swizzled Vs.
// ---------------------------------------------------------------------------
__global__ __launch_bounds__(256)
void attn_mfma(const bf16* __restrict__ Q, const bf16* __restrict__ Kb,
               const bf16* __restrict__ Vt, bf16* __restrict__ O)
{
    __shared__ __align__(16) bf16 Ks[2][64 * 64];   // [kv][hd]  swizzled
    __shared__ __align__(16) bf16 Vs[2][64 * 64];   // [d][kv]   swizzled

    const int t = threadIdx.x, lane = t & 63, w = t >> 6;
    const int h   = blockIdx.x & (NH - 1);
    const int p   = (int)(blockIdx.x >> 4);         // 0..31
    const int qiA = p, qiB = 63 - p;
    const int fr = lane & 15, fc = lane >> 4;

    // active Q frags (tile A) + standby (tile B); swapped in at the flip
    bf16x8 qf[2], qfB[2];
    #pragma unroll
    for (int kh = 0; kh < 2; ++kh) {
        qf[kh]  = *(const bf16x8*)(Q + (size_t)(qiA * 64 + w * 16 + fr) * DMODEL
                                     + h * HD + kh * 32 + fc * 8);
        qfB[kh] = *(const bf16x8*)(Q + (size_t)(qiB * 64 + w * 16 + fr) * DMODEL
                                     + h * HD + kh * 32 + fc * 8);
    }

    f32x4 o[4] = {};        // o[fd][r]: d = fd*16 + fc*4 + r, q = fr
    float lsum = 0.f;

    auto stage = [&](int buf, int kb2) {
        const int kbase2 = kb2 * 64;
        #pragma unroll
        for (int i = 0; i < 2; ++i) {
            int row = w * 16 + i * 8 + (lane >> 3);
            int gch = (lane & 7) ^ (row & 7);
            gl_lds16(Kb + (size_t)(kbase2 + row) * DMODEL + h * HD + gch * 8,
                     &Ks[buf][(w * 16 + i * 8) * 64]);
            gl_lds16(Vt + (size_t)(h * HD + row) * S_LEN + kbase2 + gch * 8,
                     &Vs[buf][(w * 16 + i * 8) * 64]);
        }
    };

    stage(0, 0);
    __syncthreads();

    int cur = 0, qi_cur = qiA, qbase_cur = qiA * 64;
    for (int tt = 0; tt < 65; ++tt) {
        const int kv_local = (tt <= qiA) ? tt : tt - qiA - 1;
        // prefetch kv-tile for step tt+1 (crosses the A->B boundary cleanly)
        if (tt < 64) {
            const int nkb = (tt + 1 <= qiA) ? tt + 1 : tt - qiA;
            stage(cur ^ 1, nkb);
        }

        // ---- S^T = K Q^T : s[fn][r] = S[q=fr][kv = fn*16 + fc*4 + r] ----
        f32x4 s[4] = {};
        #pragma unroll
        for (int fn = 0; fn < 4; ++fn)
            #pragma unroll
            for (int kh = 0; kh < 2; ++kh) {
                bf16x8 kf = *(const bf16x8*)
                    &Ks[cur][(fn * 16 + fr) * 64 + (((kh * 4 + fc) ^ (fr & 7)) * 8)];
                s[fn] = __builtin_amdgcn_mfma_f32_16x16x32_bf16(kf, qf[kh], s[fn], 0, 0, 0);
            }

        const bool diag = (kv_local == qi_cur);
        if (diag) {   // causal mask on the diagonal tile: kv > q
            #pragma unroll
            for (int fn = 0; fn < 4; ++fn)
                #pragma unroll
                for (int r = 0; r < 4; ++r)
                    if (fn * 16 + fc * 4 + r > w * 16 + fr) s[fn][r] = -INFINITY;
        }

        // ---- p = exp2(S_raw * log2e/8), in place; scalar lsum ----
        #pragma unroll
        for (int fn = 0; fn < 4; ++fn)
            #pragma unroll
            for (int r = 0; r < 4; ++r) {
                float pp = exp2f(s[fn][r] * 0.18033688011112042f);
                lsum += pp;
                s[fn][r] = pp;
            }

        // ---- O^T += V P^T with permuted k-map: k = 8*fc + 4*(fn&1) + r ----
        #pragma unroll
        for (int kvh = 0; kvh < 2; ++kvh) {
            bf16x8 pa;
            #pragma unroll
            for (int r = 0; r < 4; ++r) {
                pa[r]     = (bf16)s[2 * kvh][r];
                pa[4 + r] = (bf16)s[2 * kvh + 1][r];
            }
            #pragma unroll
            for (int fd = 0; fd < 4; ++fd) {
                const int rowb = (fd * 16 + fr) * 64 + (fc & 1) * 4;
                bf16x4 va = *(const bf16x4*)
                    &Vs[cur][rowb + (((kvh * 4     + (fc >> 1)) ^ (fr & 7)) * 8)];
                bf16x4 vb = *(const bf16x4*)
                    &Vs[cur][rowb + (((kvh * 4 + 2 + (fc >> 1)) ^ (fr & 7)) * 8)];
                bf16x8 vf;
                #pragma unroll
                for (int e = 0; e < 4; ++e) { vf[e] = va[e]; vf[4 + e] = vb[e]; }
                o[fd] = __builtin_amdgcn_mfma_f32_16x16x32_bf16(vf, pa, o[fd], 0, 0, 0);
            }
        }

        if (diag) {   // tile finished: normalize, store, reset, flip to B
            float ls = lsum;
            ls += __shfl_xor(ls, 16, 64);
            ls += __shfl_xor(ls, 32, 64);
            const float inv = 1.0f / ls;
            #pragma unroll
            for (int fd = 0; fd < 4; ++fd) {
                bf16x4 ov;
                #pragma unroll
                for (int r = 0; r < 4; ++r) ov[r] = (bf16)(o[fd][r] * inv);
                *(bf16x4*)(O + (size_t)(qbase_cur + w * 16 + fr) * DMODEL
                             + h * HD + fd * 16 + fc * 4) = ov;
                o[fd] = (f32x4){0.f, 0.f, 0.f, 0.f};
            }
            lsum = 0.f;
            qi_cur = qiB; qbase_cur = qiB * 64;
            qf[0] = qfB[0]; qf[1] = qfB[1];
        }

        __syncthreads();   // drains prefetch (vmcnt) + protects LDS bufs
        cur ^= 1;
    }
}

// ---------------------------------------------------------------------------
extern "C" void kernel_launch(void* const* d_in, const int* in_sizes, int n_in,
                              void* d_out, int out_size, void* d_ws, size_t ws_size,
                              hipStream_t stream)
{
    const float* x  = (const float*)d_in[0];
    const float* Wq = (const float*)d_in[1];
    const float* Wk = (const float*)d_in[2];
    const float* Wv = (const float*)d_in[3];
    const float* Wo = (const float*)d_in[4];

    const size_t M1 = 1024 * 1024;
    bf16* xb  = (bf16*)d_ws;          // 4M elems
    bf16* wqb = xb  + 4 * M1;         // 1M each
    bf16* wkb = wqb + M1;
    bf16* wvb = wkb + M1;
    bf16* wob = wvb + M1;
    bf16* Qb  = wob + M1;             // 4M
    bf16* Kb  = Qb  + 4 * M1;         // 4M
    bf16* Vt  = Kb  + 4 * M1;         // 4M  (transposed: [DMODEL][S])
    bf16* Ob  = Vt  + 4 * M1;         // 4M

    f32_to_bf16_all<<<4096, 256, 0, stream>>>(x, Wq, Wk, Wv, Wo,
                                              xb, wqb, wkb, wvb, wob);

    gemm_qkv<<<dim3(S_LEN / 128, DMODEL / 64, 3), 256, 0, stream>>>(
        xb, wqb, wkb, wvb, Qb, Kb, Vt);

    attn_mfma<<<dim3((S_LEN / 64) * NH / 2), 256, 0, stream>>>(Qb, Kb, Vt, Ob);

    gemm_out<<<dim3(S_LEN / 128, DMODEL / 64), 256, 0, stream>>>(
        Ob, wob, (float*)d_out);
}

// Round 11
// 218.010 us; speedup vs baseline: 1.0812x; 1.0812x over previous
//
#include <hip/hip_runtime.h>
#include <math.h>

#define S_LEN  4096
#define DMODEL 1024
#define NH     16
#define HD     64

typedef __bf16 bf16;
typedef __attribute__((ext_vector_type(8))) __bf16 bf16x8;
typedef __attribute__((ext_vector_type(4))) __bf16 bf16x4;
typedef __attribute__((ext_vector_type(4))) float  f32x4;

// direct global->LDS, 16B per lane. dest = wave-uniform base + lane*16.
__device__ inline void gl_lds16(const void* g, void* l) {
    __builtin_amdgcn_global_load_lds(
        (const __attribute__((address_space(1))) void*)g,
        (__attribute__((address_space(3))) void*)l, 16, 0, 0);
}

// ---------------------------------------------------------------------------
// fp32 -> bf16 conversion for x, Wq, Wk, Wv, Wo in one launch.
// ---------------------------------------------------------------------------
__global__ __launch_bounds__(256)
void f32_to_bf16_all(const float* __restrict__ x,  const float* __restrict__ wq,
                     const float* __restrict__ wk, const float* __restrict__ wv,
                     const float* __restrict__ wo,
                     bf16* __restrict__ xb,  bf16* __restrict__ wqb,
                     bf16* __restrict__ wkb, bf16* __restrict__ wvb,
                     bf16* __restrict__ wob)
{
    int b = blockIdx.x;
    const float* s; bf16* d; int idx;
    if      (b < 2048) { s = x;  d = xb;  idx = b; }
    else if (b < 2560) { s = wq; d = wqb; idx = b - 2048; }
    else if (b < 3072) { s = wk; d = wkb; idx = b - 2560; }
    else if (b < 3584) { s = wv; d = wvb; idx = b - 3072; }
    else               { s = wo; d = wob; idx = b - 3584; }
    size_t e0 = ((size_t)idx * 256 + threadIdx.x) * 8;
    float4 a = *(const float4*)(s + e0);
    float4 c = *(const float4*)(s + e0 + 4);
    bf16x8 r;
    r[0] = (bf16)a.x; r[1] = (bf16)a.y; r[2] = (bf16)a.z; r[3] = (bf16)a.w;
    r[4] = (bf16)c.x; r[5] = (bf16)c.y; r[6] = (bf16)c.z; r[7] = (bf16)c.w;
    *(bf16x8*)(d + e0) = r;
}

// ---------------------------------------------------------------------------
// bf16 MFMA GEMM, NT: C[m,n] = sum_k A[m,k]*B[n,k].  128x128 tile, BK=32,
// 4 waves, 2-phase LDS double-buffer with global_load_lds(16B).
// trans=true (V^T output) additionally applies the attn kv-permutation
// sigma(32*kvh+16*u+4*fc+r) = (4*kvh+fc)*8+4*u+r within each 64-row block of
// the s-dimension, so attn can read V fragments as single ds_read_b128.
// ---------------------------------------------------------------------------
template <typename OutT>
__device__ inline void gemm_body(const bf16* __restrict__ A, const bf16* __restrict__ B,
                                 OutT* __restrict__ C, bool trans, int M, int N, int K)
{
    __shared__ __align__(16) bf16 As[2][128 * 32];
    __shared__ __align__(16) bf16 Bs[2][128 * 32];

    const int t = threadIdx.x, lane = t & 63, w = t >> 6;
    const int m0 = blockIdx.x * 128, n0 = blockIdx.y * 128;
    const int wr = (w >> 1) * 64, wc = (w & 1) * 64;
    const int fr = lane & 15, fc = lane >> 4;

    const int  srow = w * 32 + (lane >> 2);
    const int  schk = (lane & 3) * 8;
    const bf16* Ag = A + (size_t)(m0 + srow) * K + schk;
    const bf16* Bg = B + (size_t)(n0 + srow) * K + schk;
    const int  sbase = (w * 32) * 32;

    f32x4 acc[4][4] = {};

    auto stage = [&](int buf, int k0) {
        gl_lds16(Ag + k0,                  &As[buf][sbase]);
        gl_lds16(Ag + k0 + (size_t)16 * K, &As[buf][sbase + 16 * 32]);
        gl_lds16(Bg + k0,                  &Bs[buf][sbase]);
        gl_lds16(Bg + k0 + (size_t)16 * K, &Bs[buf][sbase + 16 * 32]);
    };

    stage(0, 0);
    __syncthreads();
    int cur = 0;
    for (int k0 = 0; k0 < K; k0 += 32) {
        if (k0 + 32 < K) stage(cur ^ 1, k0 + 32);
        bf16x8 af[4], bv[4];
        #pragma unroll
        for (int fm = 0; fm < 4; ++fm)
            af[fm] = *(const bf16x8*)&As[cur][(wr + fm * 16 + fr) * 32 + fc * 8];
        #pragma unroll
        for (int fn = 0; fn < 4; ++fn)
            bv[fn] = *(const bf16x8*)&Bs[cur][(wc + fn * 16 + fr) * 32 + fc * 8];
        #pragma unroll
        for (int fm = 0; fm < 4; ++fm)
            #pragma unroll
            for (int fn = 0; fn < 4; ++fn)
                acc[fm][fn] = __builtin_amdgcn_mfma_f32_16x16x32_bf16(
                                  af[fm], bv[fn], acc[fm][fn], 0, 0, 0);
        __syncthreads();
        cur ^= 1;
    }

    // epilogue: D layout col=lane&15, row=(lane>>4)*4+reg
    #pragma unroll
    for (int fm = 0; fm < 4; ++fm)
        #pragma unroll
        for (int fn = 0; fn < 4; ++fn)
            #pragma unroll
            for (int r = 0; r < 4; ++r) {
                int row = m0 + wr + fm * 16 + fc * 4 + r;
                int col = n0 + wc + fn * 16 + fr;
                float v = acc[fm][fn][r];
                if (trans) {
                    int rl = row & 63;   // sigma within the 64-block (s-dim)
                    int rp = (row & ~63)
                           | ((((rl >> 5) & 1) * 4 + ((rl >> 2) & 3)) * 8
                              + ((rl >> 4) & 1) * 4 + (rl & 3));
                    C[(size_t)col * M + rp] = (OutT)v;
                } else {
                    C[(size_t)row * N + col] = (OutT)v;
                }
            }
}

__global__ __launch_bounds__(256)
void gemm_qkv(const bf16* __restrict__ A,
              const bf16* __restrict__ Wq, const bf16* __restrict__ Wk,
              const bf16* __restrict__ Wv,
              bf16* __restrict__ Qo, bf16* __restrict__ Ko, bf16* __restrict__ Vo)
{
    const int z = blockIdx.z;
    const bf16* B = (z == 0) ? Wq : (z == 1) ? Wk : Wv;
    bf16*       C = (z == 0) ? Qo : (z == 1) ? Ko : Vo;
    gemm_body<bf16>(A, B, C, z == 2, S_LEN, DMODEL, DMODEL);
}

__global__ __launch_bounds__(256)
void gemm_out(const bf16* __restrict__ A, const bf16* __restrict__ B,
              float* __restrict__ C)
{
    gemm_body<float>(A, B, C, false, S_LEN, DMODEL, DMODEL);
}

// ---------------------------------------------------------------------------
// MFMA flash attention, causal, NO-MAX softmax, swapped-operand form (R6
// structure: grid 1024, balanced qi permutation), V-path upgraded to single
// ds_read_b128 fragments via the sigma-permuted Vt (R5's all-b128 pattern
// measured 0 bank conflicts; R6's b64 pair measured 8.5e6).
//   S^T = mfma(K,Q): lane holds 16 P values for one q-row -> in-lane softmax,
//   scalar lsum reduced once in epilogue. pa<->vf k-map (both operands):
//   kv = 32*kvh + 16*(j>>2) + 4*fc + (j&3)  [j = elem index 0..7].
// K/V double-buffered (2-phase), 1 barrier/tile.
// ---------------------------------------------------------------------------
__global__ __launch_bounds__(256)
void attn_mfma(const bf16* __restrict__ Q, const bf16* __restrict__ Kb,
               const bf16* __restrict__ Vt, bf16* __restrict__ O)
{
    __shared__ __align__(16) bf16 Ks[2][64 * 64];   // [kv][hd]  swizzled
    __shared__ __align__(16) bf16 Vs[2][64 * 64];   // [d][sigma(kv)] swizzled

    const int t = threadIdx.x, lane = t & 63, w = t >> 6;
    const int h  = blockIdx.x & (NH - 1);
    const int j  = (int)(blockIdx.x >> 4);          // 0..63
    const int a  = j & 15, sg = j >> 4;
    // balanced permutation: stride-16-in-j groups sum to equal causal work.
    const int qi = (sg == 0) ? a : (sg == 1) ? 63 - a : (sg == 2) ? 16 + a : 47 - a;
    const int qbase = qi * 64;
    const int fr = lane & 15, fc = lane >> 4;

    // Q fragments in registers (raw — scale folded into exp2 constant)
    bf16x8 qf[2];
    #pragma unroll
    for (int kh = 0; kh < 2; ++kh)
        qf[kh] = *(const bf16x8*)(Q + (size_t)(qbase + w * 16 + fr) * DMODEL
                                    + h * HD + kh * 32 + fc * 8);

    f32x4 o[4] = {};        // o[fd][r]: d = fd*16 + fc*4 + r, q = fr
    float lsum = 0.f;       // row-sum partial for q-row fr

    auto stage = [&](int buf, int kb2) {
        const int kbase2 = kb2 * 64;
        #pragma unroll
        for (int i = 0; i < 2; ++i) {
            int row = w * 16 + i * 8 + (lane >> 3);
            int gch = (lane & 7) ^ (row & 7);
            gl_lds16(Kb + (size_t)(kbase2 + row) * DMODEL + h * HD + gch * 8,
                     &Ks[buf][(w * 16 + i * 8) * 64]);
            gl_lds16(Vt + (size_t)(h * HD + row) * S_LEN + kbase2 + gch * 8,
                     &Vs[buf][(w * 16 + i * 8) * 64]);
        }
    };

    stage(0, 0);
    __syncthreads();

    int cur = 0;
    for (int kb = 0; kb <= qi; ++kb) {
        if (kb < qi) stage(cur ^ 1, kb + 1);   // prefetch overlaps compute

        // ---- S^T = K Q^T : s[fn][r] = S[q=fr][kv = fn*16 + fc*4 + r] ----
        f32x4 s[4] = {};
        #pragma unroll
        for (int fn = 0; fn < 4; ++fn)
            #pragma unroll
            for (int kh = 0; kh < 2; ++kh) {
                bf16x8 kf = *(const bf16x8*)
                    &Ks[cur][(fn * 16 + fr) * 64 + (((kh * 4 + fc) ^ (fr & 7)) * 8)];
                s[fn] = __builtin_amdgcn_mfma_f32_16x16x32_bf16(kf, qf[kh], s[fn], 0, 0, 0);
            }

        if (kb == qi) {   // causal mask on the diagonal tile: kv > q
            #pragma unroll
            for (int fn = 0; fn < 4; ++fn)
                #pragma unroll
                for (int r = 0; r < 4; ++r)
                    if (fn * 16 + fc * 4 + r > w * 16 + fr) s[fn][r] = -INFINITY;
        }

        // ---- p = exp2(S_raw * log2e/8), in place; scalar lsum ----
        #pragma unroll
        for (int fn = 0; fn < 4; ++fn)
            #pragma unroll
            for (int r = 0; r < 4; ++r) {
                float p = exp2f(s[fn][r] * 0.18033688011112042f);
                lsum += p;
                s[fn][r] = p;
            }

        // ---- O^T += V P^T : V fragment = ONE b128 read (sigma layout) ----
        #pragma unroll
        for (int kvh = 0; kvh < 2; ++kvh) {
            bf16x8 pa;
            #pragma unroll
            for (int r = 0; r < 4; ++r) {
                pa[r]     = (bf16)s[2 * kvh][r];
                pa[4 + r] = (bf16)s[2 * kvh + 1][r];
            }
            #pragma unroll
            for (int fd = 0; fd < 4; ++fd) {
                bf16x8 vf = *(const bf16x8*)
                    &Vs[cur][(fd * 16 + fr) * 64 + (((kvh * 4 + fc) ^ (fr & 7)) * 8)];
                o[fd] = __builtin_amdgcn_mfma_f32_16x16x32_bf16(vf, pa, o[fd], 0, 0, 0);
            }
        }

        __syncthreads();   // drains prefetch (vmcnt) + protects LDS bufs
        cur ^= 1;
    }

    // ---- epilogue: reduce lsum across the 4 fc-lanes of this q-row ----
    lsum += __shfl_xor(lsum, 16, 64);
    lsum += __shfl_xor(lsum, 32, 64);
    const float inv = 1.0f / lsum;

    #pragma unroll
    for (int fd = 0; fd < 4; ++fd) {
        bf16x4 ov;
        #pragma unroll
        for (int r = 0; r < 4; ++r) ov[r] = (bf16)(o[fd][r] * inv);
        *(bf16x4*)(O + (size_t)(qbase + w * 16 + fr) * DMODEL
                     + h * HD + fd * 16 + fc * 4) = ov;
    }
}

// ---------------------------------------------------------------------------
extern "C" void kernel_launch(void* const* d_in, const int* in_sizes, int n_in,
                              void* d_out, int out_size, void* d_ws, size_t ws_size,
                              hipStream_t stream)
{
    const float* x  = (const float*)d_in[0];
    const float* Wq = (const float*)d_in[1];
    const float* Wk = (const float*)d_in[2];
    const float* Wv = (const float*)d_in[3];
    const float* Wo = (const float*)d_in[4];

    const size_t M1 = 1024 * 1024;
    bf16* xb  = (bf16*)d_ws;          // 4M elems
    bf16* wqb = xb  + 4 * M1;         // 1M each
    bf16* wkb = wqb + M1;
    bf16* wvb = wkb + M1;
    bf16* wob = wvb + M1;
    bf16* Qb  = wob + M1;             // 4M
    bf16* Kb  = Qb  + 4 * M1;         // 4M
    bf16* Vt  = Kb  + 4 * M1;         // 4M  ([DMODEL][S], kv sigma-permuted)
    bf16* Ob  = Vt  + 4 * M1;         // 4M

    f32_to_bf16_all<<<4096, 256, 0, stream>>>(x, Wq, Wk, Wv, Wo,
                                              xb, wqb, wkb, wvb, wob);

    gemm_qkv<<<dim3(S_LEN / 128, DMODEL / 128, 3), 256, 0, stream>>>(
        xb, wqb, wkb, wvb, Qb, Kb, Vt);

    attn_mfma<<<dim3((S_LEN / 64) * NH), 256, 0, stream>>>(Qb, Kb, Vt, Ob);

    gemm_out<<<dim3(S_LEN / 128, DMODEL / 128), 256, 0, stream>>>(
        Ob, wob, (float*)d_out);
}